// Round 2
// 260.250 us; speedup vs baseline: 1.0360x; 1.0360x over previous
//
#include <hip/hip_runtime.h>
#include <hip/hip_fp16.h>
#include <math.h>

// ws float layout (header only):
//  [0] E_sum  [1] tr_gp  [2..17] m[16]  [18..33] cs[16]
//  [64..2112)   B[16][128]   (written by k_reduce)
//  [2112..4160) P2[16][128]  (written by k_finalize)
// Scratch lives in the d_out features_pooled region (dead until k_unpool,
// which runs last and overwrites all of it):
//  out0[0      .. 800000)  Ah[N][16] fp16 shadow of assignments (3.2 MB)
//  out0[800000 .. 812512)  csp[GA][16] cluster-size partials (GA=782)
//  out0[825008 .. 853142)  ep[GE][18]  edge partials (GE=1563)
//  out0[861872 .. +GB*2048) bp[GB][2048] B partials (GB=1024)
// No atomics anywhere; nothing needs zero-init.

#define WS_ESUM 0
#define WS_TR   1
#define WS_M    2
#define WS_CS   18
#define WS_B    64
#define WS_P2   2112

#define OFF_AH  0
#define OFF_CSP 800000
#define OFF_EP  825008
#define OFF_BP  861872

typedef int   int4v   __attribute__((ext_vector_type(4)));
typedef float float4v __attribute__((ext_vector_type(4)));

// ---------------------------------------------------------------- k_assign
// Quad layout: 4 lanes per node, each lane covers 32 channels.
// v2: 2 nodes per thread (128 nodes/block) + bank-conflict-free padded W
// layout: Ws[k][p][36] (p-stride 36 floats -> p*36%32 = 4p -> the four
// float4 reads cover 16 distinct banks; 16-lane same-address broadcast).
__global__ __launch_bounds__(256) void k_assign(
    const float* __restrict__ F, const float* __restrict__ W,
    const float* __restrict__ bias, float* __restrict__ A,
    __half* __restrict__ Ah, float* __restrict__ csp, int N) {
  __shared__ float Ws[16 * 144];   // [k][p][36], 9216 B
  __shared__ float csred[4][16];
  int t = threadIdx.x;
#pragma unroll
  for (int i = 0; i < 8; i++) {
    int idx = t + 256 * i;         // 2048 = 16*128 elements
    int k = idx >> 7, r = idx & 127;
    Ws[k * 144 + (r >> 5) * 36 + (r & 31)] = W[idx];
  }
  __syncthreads();

  int p = t & 3;                   // quad part: channels p*32 .. p*32+31
  int slot = t >> 2;               // node slot (0..63)
  int n0 = blockIdx.x * 128 + slot;
  int n1 = n0 + 64;
  bool act0 = (n0 < N), act1 = (n1 < N);
  int n0c = act0 ? n0 : (N - 1);   // clamp: always-in-bounds loads
  int n1c = act1 ? n1 : (N - 1);

  float a0[16], a1[16];
#pragma unroll
  for (int k = 0; k < 16; k++) { a0[k] = 0.f; a1[k] = 0.f; }

  const float4* f0 = (const float4*)(F + (size_t)n0c * 128 + p * 32);
  const float4* f1 = (const float4*)(F + (size_t)n1c * 128 + p * 32);
#pragma unroll
  for (int i = 0; i < 8; i++) {
    float4 x0 = f0[i];
    float4 x1 = f1[i];
#pragma unroll
    for (int k = 0; k < 16; k++) {
      float4 w = *(const float4*)(&Ws[k * 144 + p * 36 + i * 4]);
      a0[k] = fmaf(x0.x, w.x, a0[k]);
      a0[k] = fmaf(x0.y, w.y, a0[k]);
      a0[k] = fmaf(x0.z, w.z, a0[k]);
      a0[k] = fmaf(x0.w, w.w, a0[k]);
      a1[k] = fmaf(x1.x, w.x, a1[k]);
      a1[k] = fmaf(x1.y, w.y, a1[k]);
      a1[k] = fmaf(x1.z, w.z, a1[k]);
      a1[k] = fmaf(x1.w, w.w, a1[k]);
    }
  }

#pragma unroll
  for (int k = 0; k < 16; k++) {
    a0[k] += __shfl_xor(a0[k], 1, 64);
    a0[k] += __shfl_xor(a0[k], 2, 64);
    a1[k] += __shfl_xor(a1[k], 1, 64);
    a1[k] += __shfl_xor(a1[k], 2, 64);
  }

#pragma unroll
  for (int k = 0; k < 16; k++) { a0[k] += bias[k]; a1[k] += bias[k]; }

  // softmax (both nodes, all 4 p-lanes redundantly)
  float mx0 = a0[0], mx1 = a1[0];
#pragma unroll
  for (int k = 1; k < 16; k++) { mx0 = fmaxf(mx0, a0[k]); mx1 = fmaxf(mx1, a1[k]); }
  float s0 = 0.f, s1 = 0.f;
#pragma unroll
  for (int k = 0; k < 16; k++) {
    a0[k] = __expf(a0[k] - mx0); s0 += a0[k];
    a1[k] = __expf(a1[k] - mx1); s1 += a1[k];
  }
  float inv0 = 1.0f / s0, inv1 = 1.0f / s1;
#pragma unroll
  for (int k = 0; k < 16; k++) { a0[k] *= inv0; a1[k] *= inv1; }

  if (act0)
    ((float4*)(A + (size_t)n0 * 16))[p] =
        make_float4(a0[p * 4 + 0], a0[p * 4 + 1], a0[p * 4 + 2], a0[p * 4 + 3]);
  if (act1)
    ((float4*)(A + (size_t)n1 * 16))[p] =
        make_float4(a1[p * 4 + 0], a1[p * 4 + 1], a1[p * 4 + 2], a1[p * 4 + 3]);

  // fp16 shadow: p==0/1 write node n0 halves, p==2/3 write node n1 halves
  if (p == 0 && act0) {
    __half2 hh[4];
    hh[0].x = __float2half_rn(a0[0]); hh[0].y = __float2half_rn(a0[1]);
    hh[1].x = __float2half_rn(a0[2]); hh[1].y = __float2half_rn(a0[3]);
    hh[2].x = __float2half_rn(a0[4]); hh[2].y = __float2half_rn(a0[5]);
    hh[3].x = __float2half_rn(a0[6]); hh[3].y = __float2half_rn(a0[7]);
    *(uint4*)(Ah + (size_t)n0 * 16) = *(uint4*)hh;
  } else if (p == 1 && act0) {
    __half2 hh[4];
    hh[0].x = __float2half_rn(a0[8]);  hh[0].y = __float2half_rn(a0[9]);
    hh[1].x = __float2half_rn(a0[10]); hh[1].y = __float2half_rn(a0[11]);
    hh[2].x = __float2half_rn(a0[12]); hh[2].y = __float2half_rn(a0[13]);
    hh[3].x = __float2half_rn(a0[14]); hh[3].y = __float2half_rn(a0[15]);
    *(uint4*)(Ah + (size_t)n0 * 16 + 8) = *(uint4*)hh;
  } else if (p == 2 && act1) {
    __half2 hh[4];
    hh[0].x = __float2half_rn(a1[0]); hh[0].y = __float2half_rn(a1[1]);
    hh[1].x = __float2half_rn(a1[2]); hh[1].y = __float2half_rn(a1[3]);
    hh[2].x = __float2half_rn(a1[4]); hh[2].y = __float2half_rn(a1[5]);
    hh[3].x = __float2half_rn(a1[6]); hh[3].y = __float2half_rn(a1[7]);
    *(uint4*)(Ah + (size_t)n1 * 16) = *(uint4*)hh;
  } else if (p == 3 && act1) {
    __half2 hh[4];
    hh[0].x = __float2half_rn(a1[8]);  hh[0].y = __float2half_rn(a1[9]);
    hh[1].x = __float2half_rn(a1[10]); hh[1].y = __float2half_rn(a1[11]);
    hh[2].x = __float2half_rn(a1[12]); hh[2].y = __float2half_rn(a1[13]);
    hh[3].x = __float2half_rn(a1[14]); hh[3].y = __float2half_rn(a1[15]);
    *(uint4*)(Ah + (size_t)n1 * 16 + 8) = *(uint4*)hh;
  }

  // cluster-size partials
  int lane = t & 63, wid = t >> 6;
#pragma unroll
  for (int k = 0; k < 16; k++) {
    float v = 0.f;
    if (p == 0) {
      if (act0) v += a0[k];
      if (act1) v += a1[k];
    }
    for (int off = 32; off; off >>= 1) v += __shfl_xor(v, off, 64);
    if (lane == 0) csred[wid][k] = v;
  }
  __syncthreads();
  if (t < 16)
    csp[(size_t)blockIdx.x * 16 + t] =
        csred[0][t] + csred[1][t] + csred[2][t] + csred[3][t];
}

// ---------------------------------------------------------------- k_edge
// v2: 4 consecutive edges per thread per iteration. Index/val loads are one
// int4/int4/float4 each (coalesced, nontemporal: the 38 MB edge stream must
// not evict the 3.2 MB Ah table from L2). All 16 gathers issued before any
// convert/FMA -> 16 loads in flight per thread.
union H2F4 { float4 f4; __half2 h2[4]; };

__device__ __forceinline__ void edge_body(
    const __half* __restrict__ Ah, int r, int c, float v,
    float& eS, float& tr, float* m) {
  const float4* pc = (const float4*)(Ah + (size_t)c * 16);
  const float4* pr = (const float4*)(Ah + (size_t)r * 16);
  H2F4 uc0, uc1, ur0, ur1;
  uc0.f4 = pc[0]; uc1.f4 = pc[1];
  ur0.f4 = pr[0]; ur1.f4 = pr[1];
  float cf[16], rf[16];
#pragma unroll
  for (int j = 0; j < 4; j++) {
    float2 f;
    f = __half22float2(uc0.h2[j]); cf[2 * j] = f.x; cf[2 * j + 1] = f.y;
    f = __half22float2(uc1.h2[j]); cf[8 + 2 * j] = f.x; cf[9 + 2 * j] = f.y;
    f = __half22float2(ur0.h2[j]); rf[2 * j] = f.x; rf[2 * j + 1] = f.y;
    f = __half22float2(ur1.h2[j]); rf[8 + 2 * j] = f.x; rf[9 + 2 * j] = f.y;
  }
  eS += v;
  float d = 0.f;
#pragma unroll
  for (int k = 0; k < 16; k++) {
    m[k] = fmaf(v, cf[k], m[k]);
    d = fmaf(rf[k], cf[k], d);
  }
  tr = fmaf(v, d, tr);
}

__device__ __forceinline__ void group4(
    const __half* __restrict__ Ah, const int* __restrict__ row,
    const int* __restrict__ col, const float* __restrict__ val, int e,
    float& eS, float& tr, float* m) {
  int4v   ri = __builtin_nontemporal_load((const int4v*)(row + e));
  int4v   ci = __builtin_nontemporal_load((const int4v*)(col + e));
  float4v vi = __builtin_nontemporal_load((const float4v*)(val + e));

  H2F4 CA[4][2], RA[4][2];
#pragma unroll
  for (int j = 0; j < 4; j++) {
    const float4* pc = (const float4*)(Ah + (size_t)ci[j] * 16);
    const float4* pr = (const float4*)(Ah + (size_t)ri[j] * 16);
    CA[j][0].f4 = pc[0]; CA[j][1].f4 = pc[1];
    RA[j][0].f4 = pr[0]; RA[j][1].f4 = pr[1];
  }

#pragma unroll
  for (int j = 0; j < 4; j++) {
    float vj = vi[j];
    float cf[16], rf[16];
#pragma unroll
    for (int q = 0; q < 4; q++) {
      float2 f;
      f = __half22float2(CA[j][0].h2[q]); cf[2 * q] = f.x; cf[2 * q + 1] = f.y;
      f = __half22float2(CA[j][1].h2[q]); cf[8 + 2 * q] = f.x; cf[9 + 2 * q] = f.y;
      f = __half22float2(RA[j][0].h2[q]); rf[2 * q] = f.x; rf[2 * q + 1] = f.y;
      f = __half22float2(RA[j][1].h2[q]); rf[8 + 2 * q] = f.x; rf[9 + 2 * q] = f.y;
    }
    eS += vj;
    float d = 0.f;
#pragma unroll
    for (int k = 0; k < 16; k++) {
      m[k] = fmaf(vj, cf[k], m[k]);
      d = fmaf(rf[k], cf[k], d);
    }
    tr = fmaf(vj, d, tr);
  }
}

__global__ __launch_bounds__(256) void k_edge(
    const int* __restrict__ row, const int* __restrict__ col,
    const float* __restrict__ val, const __half* __restrict__ Ah,
    float* __restrict__ ep, int E) {
  float eS = 0.f, tr = 0.f;
  float m[16];
#pragma unroll
  for (int i = 0; i < 16; i++) m[i] = 0.f;

  int gid = blockIdx.x * 256 + threadIdx.x;
  int T4 = gridDim.x * 256 * 4;
  int E4 = E & ~3;
  for (int e = gid * 4; e < E4; e += T4)
    group4(Ah, row, col, val, e, eS, tr, m);
  // tail (E % 4 edges)
  if (gid < E - E4)
    edge_body(Ah, row[E4 + gid], col[E4 + gid], val[E4 + gid], eS, tr, m);

  float vals[18];
  vals[0] = eS; vals[1] = tr;
#pragma unroll
  for (int i = 0; i < 16; i++) vals[2 + i] = m[i];
#pragma unroll
  for (int i = 0; i < 18; i++) {
    float v = vals[i];
    for (int off = 32; off; off >>= 1) v += __shfl_xor(v, off, 64);
    vals[i] = v;
  }
  __shared__ float red[4][18];
  int lane = threadIdx.x & 63, wid = threadIdx.x >> 6;
  if (lane == 0) {
#pragma unroll
    for (int i = 0; i < 18; i++) red[wid][i] = vals[i];
  }
  __syncthreads();
  if (threadIdx.x < 18)
    ep[(size_t)blockIdx.x * 18 + threadIdx.x] =
        red[0][threadIdx.x] + red[1][threadIdx.x] +
        red[2][threadIdx.x] + red[3][threadIdx.x];
}

// ---------------------------------------------------------------- k_nodeB
// Block partials of B[k,c]; wave F loads = one contiguous 1 KB. (unchanged)
__global__ __launch_bounds__(256) void k_nodeB(
    const float* __restrict__ F, const float* __restrict__ A,
    float* __restrict__ bp, int N) {
  int t = threadIdx.x;
  int q = t & 31;
  int sub = t >> 5;

  float4 acc[16];
#pragma unroll
  for (int k = 0; k < 16; k++) acc[k] = make_float4(0.f, 0.f, 0.f, 0.f);

  const float4* F4 = (const float4*)F;
  const float4* A4 = (const float4*)A;
  int stride = gridDim.x * 8;
  for (int n = blockIdx.x * 8 + sub; n < N; n += stride) {
    float4 f  = F4[(size_t)n * 32 + q];
    float4 a0 = A4[(size_t)n * 4 + 0];
    float4 a1 = A4[(size_t)n * 4 + 1];
    float4 a2 = A4[(size_t)n * 4 + 2];
    float4 a3 = A4[(size_t)n * 4 + 3];
    float av[16] = {a0.x, a0.y, a0.z, a0.w, a1.x, a1.y, a1.z, a1.w,
                    a2.x, a2.y, a2.z, a2.w, a3.x, a3.y, a3.z, a3.w};
#pragma unroll
    for (int k = 0; k < 16; k++) {
      acc[k].x = fmaf(av[k], f.x, acc[k].x);
      acc[k].y = fmaf(av[k], f.y, acc[k].y);
      acc[k].z = fmaf(av[k], f.z, acc[k].z);
      acc[k].w = fmaf(av[k], f.w, acc[k].w);
    }
  }

#pragma unroll
  for (int k = 0; k < 16; k++) {
    acc[k].x += __shfl_xor(acc[k].x, 32, 64);
    acc[k].y += __shfl_xor(acc[k].y, 32, 64);
    acc[k].z += __shfl_xor(acc[k].z, 32, 64);
    acc[k].w += __shfl_xor(acc[k].w, 32, 64);
  }

  __shared__ float red[4][2048];   // 32 KB
  int lane = t & 63, wid = t >> 6;
  if (lane < 32) {
#pragma unroll
    for (int k = 0; k < 16; k++)
      *(float4*)&red[wid][k * 128 + q * 4] = acc[k];
  }
  __syncthreads();
  float* myp = bp + (size_t)blockIdx.x * 2048;
#pragma unroll
  for (int qq = 0; qq < 2; qq++) {
    int base = t * 8 + qq * 4;
    float4 s0 = *(float4*)&red[0][base];
    float4 s1 = *(float4*)&red[1][base];
    float4 s2 = *(float4*)&red[2][base];
    float4 s3 = *(float4*)&red[3][base];
    *(float4*)&myp[base] = make_float4(s0.x + s1.x + s2.x + s3.x,
                                       s0.y + s1.y + s2.y + s3.y,
                                       s0.z + s1.z + s2.z + s3.z,
                                       s0.w + s1.w + s2.w + s3.w);
  }
}

// ---------------------------------------------------------------- k_reduce
// 258 blocks, ILP-unrolled. (unchanged)
__global__ __launch_bounds__(256) void k_reduce(
    const float* __restrict__ csp, const float* __restrict__ ep,
    const float* __restrict__ bp, float* __restrict__ ws,
    int GA, int GE, int GB) {
  __shared__ float L[256];
  int t = threadIdx.x;
  int b = blockIdx.x;
  if (b < 256) {
    int cell = b * 8 + (t & 7);
    int seg = t >> 3;                      // 0..31
    float s0 = 0.f, s1 = 0.f, s2 = 0.f, s3 = 0.f;
    int g = seg;
    for (; g + 96 < GB; g += 128) {
      s0 += bp[(size_t)g * 2048 + cell];
      s1 += bp[(size_t)(g + 32) * 2048 + cell];
      s2 += bp[(size_t)(g + 64) * 2048 + cell];
      s3 += bp[(size_t)(g + 96) * 2048 + cell];
    }
    for (; g < GB; g += 32) s0 += bp[(size_t)g * 2048 + cell];
    L[t] = (s0 + s1) + (s2 + s3);
    __syncthreads();
    if (t < 8) {
      float tot = 0.f;
#pragma unroll
      for (int s = 0; s < 32; s++) tot += L[s * 8 + t];
      ws[WS_B + b * 8 + t] = tot;
    }
  } else if (b == 256) {
    int n = GE * 18;
    float s0 = 0.f, s1 = 0.f, s2 = 0.f, s3 = 0.f;
    if (t < 252) {
      int f = t;
      for (; f + 756 < n; f += 1008) {
        s0 += ep[f]; s1 += ep[f + 252]; s2 += ep[f + 504]; s3 += ep[f + 756];
      }
      for (; f < n; f += 252) s0 += ep[f];
    }
    L[t] = (s0 + s1) + (s2 + s3);
    __syncthreads();
    if (t < 18) {
      float tot = 0.f;
#pragma unroll
      for (int j = 0; j < 14; j++) tot += L[j * 18 + t];
      ws[t] = tot;                        // E_sum, tr, m[16]
    }
  } else {
    int n = GA * 16;
    float s0 = 0.f, s1 = 0.f, s2 = 0.f, s3 = 0.f;
    int f = t;
    for (; f + 768 < n; f += 1024) {
      s0 += csp[f]; s1 += csp[f + 256]; s2 += csp[f + 512]; s3 += csp[f + 768];
    }
    for (; f < n; f += 256) s0 += csp[f];
    L[t] = (s0 + s1) + (s2 + s3);
    __syncthreads();
    if (t < 16) {
      float tot = 0.f;
#pragma unroll
      for (int j = 0; j < 16; j++) tot += L[j * 16 + t];
      ws[WS_CS + t] = tot;
    }
  }
}

// ---------------------------------------------------------------- k_finalize
__global__ __launch_bounds__(256) void k_finalize(
    float* __restrict__ ws, float* __restrict__ loss_out, int N) {
  __shared__ float invcs[16];
  int t = threadIdx.x;
  if (t < 16) invcs[t] = 1.0f / ws[WS_CS + t];
  __syncthreads();
  const float* B = ws + WS_B;
  float* P2 = ws + WS_P2;
  const float scale = 1.0507009873554805f;
  const float alpha = 1.6732632423543772f;
#pragma unroll
  for (int idx = t; idx < 2048; idx += 256) {
    int k = idx >> 7;
    float x = B[idx] * invcs[k];
    float s = (x > 0.f) ? scale * x : scale * alpha * expm1f(x);
    P2[idx] = s * invcs[k];
  }
  if (t == 0) {
    float Es = ws[WS_ESUM], tr = ws[WS_TR];
    float m2 = 0.f;
#pragma unroll
    for (int i = 0; i < 16; i++) m2 += ws[WS_M + i] * ws[WS_M + i];
    float spectral = -(tr - m2 / (2.0f * Es)) / (2.0f * Es);
    float coll = 0.f;
    float tgt = (float)N / 16.0f;
#pragma unroll
    for (int i = 0; i < 16; i++) coll += fabsf(ws[WS_CS + i] - tgt);
    coll = coll / (float)N * (4.0f / 3.0f / 2.0f);  // sk/(sk-1)/2, sk=4
    loss_out[0] = spectral + coll;
  }
}

// ---------------------------------------------------------------- k_unpool
// out[n,c] = sum_k A[n,k] * P2[k,c]   (runs LAST — overwrites scratch)
// v2: P2 hoisted into 16 float4 registers per thread (loop-invariant),
// 4 channels per thread, float4 stores. 8 nodes per block-iteration.
__global__ __launch_bounds__(256) void k_unpool(
    const float* __restrict__ A, const float* __restrict__ P2,
    float* __restrict__ out, int N) {
  __shared__ float Ps[2048];
  int t = threadIdx.x;
#pragma unroll
  for (int i = 0; i < 8; i++) Ps[t + 256 * i] = P2[t + 256 * i];
  __syncthreads();
  int c4 = (t & 31) << 2;          // channel base (0,4,...,124)
  int sub = t >> 5;                // 0..7 (node within group)
  float4 pk[16];
#pragma unroll
  for (int k = 0; k < 16; k++) pk[k] = *(const float4*)&Ps[k * 128 + c4];

  int stride = gridDim.x * 8;
  for (int n = blockIdx.x * 8 + sub; n < N; n += stride) {
    const float4* a4 = (const float4*)(A + (size_t)n * 16);
    float4 a0 = a4[0], a1 = a4[1], a2 = a4[2], a3 = a4[3];
    float av[16] = {a0.x, a0.y, a0.z, a0.w, a1.x, a1.y, a1.z, a1.w,
                    a2.x, a2.y, a2.z, a2.w, a3.x, a3.y, a3.z, a3.w};
    float4 s = make_float4(0.f, 0.f, 0.f, 0.f);
#pragma unroll
    for (int k = 0; k < 16; k++) {
      s.x = fmaf(av[k], pk[k].x, s.x);
      s.y = fmaf(av[k], pk[k].y, s.y);
      s.z = fmaf(av[k], pk[k].z, s.z);
      s.w = fmaf(av[k], pk[k].w, s.w);
    }
    *(float4*)(out + (size_t)n * 128 + c4) = s;
  }
}

// ----------------------------------------------------------------
extern "C" void kernel_launch(void* const* d_in, const int* in_sizes, int n_in,
                              void* d_out, int out_size, void* d_ws, size_t ws_size,
                              hipStream_t stream) {
  const float* F    = (const float*)d_in[0];  // [N,128]
  const int*   erow = (const int*)d_in[1];    // [E]
  const int*   ecol = (const int*)d_in[2];    // [E]
  const float* eval_= (const float*)d_in[3];  // [E]
  const float* W    = (const float*)d_in[4];  // [16,128]
  const float* bias = (const float*)d_in[5];  // [16]

  int N = in_sizes[0] / 128;
  int E = in_sizes[1];

  float* out0 = (float*)d_out;                 // features_pooled [N,128]
  float* A    = out0 + (size_t)N * 128;        // assignments [N,16]
  float* loss = A + (size_t)N * 16;            // scalar
  float* ws   = (float*)d_ws;

  int GA = (N + 127) / 128;                    // k_assign grid (782)
  int GE = 1563;                               // k_edge grid (~2 iters/thread)
  int GB = 1024;                               // k_nodeB grid

  // scratch inside the (not-yet-written) features_pooled output region
  __half* Ah  = (__half*)(out0 + OFF_AH);      // [N][16] fp16, 3.2 MB
  float*  csp = out0 + OFF_CSP;                // [GA][16]
  float*  ep  = out0 + OFF_EP;                 // [GE][18]
  float*  bp  = out0 + OFF_BP;                 // [GB][2048]

  k_assign<<<GA, 256, 0, stream>>>(F, W, bias, A, Ah, csp, N);
  k_edge<<<GE, 256, 0, stream>>>(erow, ecol, eval_, Ah, ep, E);
  k_nodeB<<<GB, 256, 0, stream>>>(F, A, bp, N);
  k_reduce<<<258, 256, 0, stream>>>(csp, ep, bp, ws, GA, GE, GB);
  k_finalize<<<1, 256, 0, stream>>>(ws, loss, N);
  k_unpool<<<1280, 256, 0, stream>>>(A, ws + WS_P2, out0, N);
}

// Round 3
// 246.848 us; speedup vs baseline: 1.0923x; 1.0543x over previous
//
#include <hip/hip_runtime.h>
#include <hip/hip_fp16.h>
#include <math.h>

// ws float layout (header only):
//  [0] E_sum  [1] tr_gp  [2..17] m[16]  [18..33] cs[16]
//  [64..2112)   B[16][128]   (written by k_reduce)
// Scratch lives in the d_out features_pooled region (dead until k_unpool,
// which runs last and overwrites all of it):
//  out0[0      .. 800000)  Ah[N][16] fp16 shadow of assignments (3.2 MB)
//  out0[800000 .. 812512)  csp[GA][16] cluster-size partials (GA=782)
//  out0[825008 .. 861872)  ep[2048][18] edge partials (exactly fits)
//  out0[861872 .. +2048*2048) bp[2048][2048] B partial rows (16.8 MB)
// No atomics anywhere; nothing needs zero-init.

#define WS_ESUM 0
#define WS_TR   1
#define WS_M    2
#define WS_CS   18
#define WS_B    64

#define OFF_AH  0
#define OFF_CSP 800000
#define OFF_EP  825008
#define OFF_BP  861872

#define GE_BLOCKS 2048   // edge role blocks in fused kernel
#define GB_BLOCKS 512    // nodeB role blocks (4 waves -> 2048 partial rows)

typedef int   int4v   __attribute__((ext_vector_type(4)));
typedef float float2v __attribute__((ext_vector_type(2)));
typedef float float4v __attribute__((ext_vector_type(4)));

// ---------------------------------------------------------------- k_assign
// (unchanged from round 2 — verified win: conflict-free padded W layout,
// 2 nodes/thread)
__global__ __launch_bounds__(256) void k_assign(
    const float* __restrict__ F, const float* __restrict__ W,
    const float* __restrict__ bias, float* __restrict__ A,
    __half* __restrict__ Ah, float* __restrict__ csp, int N) {
  __shared__ float Ws[16 * 144];   // [k][p][36], 9216 B
  __shared__ float csred[4][16];
  int t = threadIdx.x;
#pragma unroll
  for (int i = 0; i < 8; i++) {
    int idx = t + 256 * i;         // 2048 = 16*128 elements
    int k = idx >> 7, r = idx & 127;
    Ws[k * 144 + (r >> 5) * 36 + (r & 31)] = W[idx];
  }
  __syncthreads();

  int p = t & 3;                   // quad part: channels p*32 .. p*32+31
  int slot = t >> 2;               // node slot (0..63)
  int n0 = blockIdx.x * 128 + slot;
  int n1 = n0 + 64;
  bool act0 = (n0 < N), act1 = (n1 < N);
  int n0c = act0 ? n0 : (N - 1);   // clamp: always-in-bounds loads
  int n1c = act1 ? n1 : (N - 1);

  float a0[16], a1[16];
#pragma unroll
  for (int k = 0; k < 16; k++) { a0[k] = 0.f; a1[k] = 0.f; }

  const float4* f0 = (const float4*)(F + (size_t)n0c * 128 + p * 32);
  const float4* f1 = (const float4*)(F + (size_t)n1c * 128 + p * 32);
#pragma unroll
  for (int i = 0; i < 8; i++) {
    float4 x0 = f0[i];
    float4 x1 = f1[i];
#pragma unroll
    for (int k = 0; k < 16; k++) {
      float4 w = *(const float4*)(&Ws[k * 144 + p * 36 + i * 4]);
      a0[k] = fmaf(x0.x, w.x, a0[k]);
      a0[k] = fmaf(x0.y, w.y, a0[k]);
      a0[k] = fmaf(x0.z, w.z, a0[k]);
      a0[k] = fmaf(x0.w, w.w, a0[k]);
      a1[k] = fmaf(x1.x, w.x, a1[k]);
      a1[k] = fmaf(x1.y, w.y, a1[k]);
      a1[k] = fmaf(x1.z, w.z, a1[k]);
      a1[k] = fmaf(x1.w, w.w, a1[k]);
    }
  }

#pragma unroll
  for (int k = 0; k < 16; k++) {
    a0[k] += __shfl_xor(a0[k], 1, 64);
    a0[k] += __shfl_xor(a0[k], 2, 64);
    a1[k] += __shfl_xor(a1[k], 1, 64);
    a1[k] += __shfl_xor(a1[k], 2, 64);
  }

#pragma unroll
  for (int k = 0; k < 16; k++) { a0[k] += bias[k]; a1[k] += bias[k]; }

  float mx0 = a0[0], mx1 = a1[0];
#pragma unroll
  for (int k = 1; k < 16; k++) { mx0 = fmaxf(mx0, a0[k]); mx1 = fmaxf(mx1, a1[k]); }
  float s0 = 0.f, s1 = 0.f;
#pragma unroll
  for (int k = 0; k < 16; k++) {
    a0[k] = __expf(a0[k] - mx0); s0 += a0[k];
    a1[k] = __expf(a1[k] - mx1); s1 += a1[k];
  }
  float inv0 = 1.0f / s0, inv1 = 1.0f / s1;
#pragma unroll
  for (int k = 0; k < 16; k++) { a0[k] *= inv0; a1[k] *= inv1; }

  if (act0)
    ((float4*)(A + (size_t)n0 * 16))[p] =
        make_float4(a0[p * 4 + 0], a0[p * 4 + 1], a0[p * 4 + 2], a0[p * 4 + 3]);
  if (act1)
    ((float4*)(A + (size_t)n1 * 16))[p] =
        make_float4(a1[p * 4 + 0], a1[p * 4 + 1], a1[p * 4 + 2], a1[p * 4 + 3]);

  if (p == 0 && act0) {
    __half2 hh[4];
    hh[0].x = __float2half_rn(a0[0]); hh[0].y = __float2half_rn(a0[1]);
    hh[1].x = __float2half_rn(a0[2]); hh[1].y = __float2half_rn(a0[3]);
    hh[2].x = __float2half_rn(a0[4]); hh[2].y = __float2half_rn(a0[5]);
    hh[3].x = __float2half_rn(a0[6]); hh[3].y = __float2half_rn(a0[7]);
    *(uint4*)(Ah + (size_t)n0 * 16) = *(uint4*)hh;
  } else if (p == 1 && act0) {
    __half2 hh[4];
    hh[0].x = __float2half_rn(a0[8]);  hh[0].y = __float2half_rn(a0[9]);
    hh[1].x = __float2half_rn(a0[10]); hh[1].y = __float2half_rn(a0[11]);
    hh[2].x = __float2half_rn(a0[12]); hh[2].y = __float2half_rn(a0[13]);
    hh[3].x = __float2half_rn(a0[14]); hh[3].y = __float2half_rn(a0[15]);
    *(uint4*)(Ah + (size_t)n0 * 16 + 8) = *(uint4*)hh;
  } else if (p == 2 && act1) {
    __half2 hh[4];
    hh[0].x = __float2half_rn(a1[0]); hh[0].y = __float2half_rn(a1[1]);
    hh[1].x = __float2half_rn(a1[2]); hh[1].y = __float2half_rn(a1[3]);
    hh[2].x = __float2half_rn(a1[4]); hh[2].y = __float2half_rn(a1[5]);
    hh[3].x = __float2half_rn(a1[6]); hh[3].y = __float2half_rn(a1[7]);
    *(uint4*)(Ah + (size_t)n1 * 16) = *(uint4*)hh;
  } else if (p == 3 && act1) {
    __half2 hh[4];
    hh[0].x = __float2half_rn(a1[8]);  hh[0].y = __float2half_rn(a1[9]);
    hh[1].x = __float2half_rn(a1[10]); hh[1].y = __float2half_rn(a1[11]);
    hh[2].x = __float2half_rn(a1[12]); hh[2].y = __float2half_rn(a1[13]);
    hh[3].x = __float2half_rn(a1[14]); hh[3].y = __float2half_rn(a1[15]);
    *(uint4*)(Ah + (size_t)n1 * 16 + 8) = *(uint4*)hh;
  }

  int lane = t & 63, wid = t >> 6;
#pragma unroll
  for (int k = 0; k < 16; k++) {
    float v = 0.f;
    if (p == 0) {
      if (act0) v += a0[k];
      if (act1) v += a1[k];
    }
    for (int off = 32; off; off >>= 1) v += __shfl_xor(v, off, 64);
    if (lane == 0) csred[wid][k] = v;
  }
  __syncthreads();
  if (t < 16)
    csp[(size_t)blockIdx.x * 16 + t] =
        csred[0][t] + csred[1][t] + csred[2][t] + csred[3][t];
}

// ---------------------------------------------------------------- fused
// k_edge_nodeB: block roles interleaved 4 edge : 1 nodeB.
//  edge role (round-0 proven structure, VGPR ~32, nt on streams):
//    strided 2-edge unroll, fp16 gathers from Ah.
//  nodeB role (new, 32 acc VGPRs): each WAVE owns whole nodes;
//    lane = channel pair -> no cross-lane/cross-wave reduction at all;
//    each wave writes its own partial row bp[nb*4+wid][2048].
//    nt on the 51 MB F stream so it doesn't evict Ah from L2.
union H2F4 { float4 f4; __half2 h2[4]; };

__device__ __forceinline__ void edge_body(
    const __half* __restrict__ Ah, int r, int c, float v,
    float& eS, float& tr, float* m) {
  const float4* pc = (const float4*)(Ah + (size_t)c * 16);
  const float4* pr = (const float4*)(Ah + (size_t)r * 16);
  H2F4 uc0, uc1, ur0, ur1;
  uc0.f4 = pc[0]; uc1.f4 = pc[1];
  ur0.f4 = pr[0]; ur1.f4 = pr[1];
  float cf[16], rf[16];
#pragma unroll
  for (int j = 0; j < 4; j++) {
    float2 f;
    f = __half22float2(uc0.h2[j]); cf[2 * j] = f.x; cf[2 * j + 1] = f.y;
    f = __half22float2(uc1.h2[j]); cf[8 + 2 * j] = f.x; cf[9 + 2 * j] = f.y;
    f = __half22float2(ur0.h2[j]); rf[2 * j] = f.x; rf[2 * j + 1] = f.y;
    f = __half22float2(ur1.h2[j]); rf[8 + 2 * j] = f.x; rf[9 + 2 * j] = f.y;
  }
  eS += v;
  float d = 0.f;
#pragma unroll
  for (int k = 0; k < 16; k++) {
    m[k] = fmaf(v, cf[k], m[k]);
    d = fmaf(rf[k], cf[k], d);
  }
  tr = fmaf(v, d, tr);
}

__global__ __launch_bounds__(256, 8) void k_edge_nodeB(
    const int* __restrict__ row, const int* __restrict__ col,
    const float* __restrict__ val, const __half* __restrict__ Ah,
    const float* __restrict__ F, const float* __restrict__ A,
    float* __restrict__ ep, float* __restrict__ bp, int E, int N) {
  __shared__ float red[4][18];
  int b = blockIdx.x;
  int t = threadIdx.x;
  bool isNode = ((b % 5) == 4);

  if (!isNode) {
    // ---------------- edge role: eb in [0, GE_BLOCKS)
    int eb = b - b / 5;
    float eS = 0.f, tr = 0.f;
    float m[16];
#pragma unroll
    for (int i = 0; i < 16; i++) m[i] = 0.f;

    int tid = eb * 256 + t;
    const int T = GE_BLOCKS * 256;
    int e = tid;
    for (; e + T < E; e += 2 * T) {
      int   r0 = __builtin_nontemporal_load(row + e);
      int   c0 = __builtin_nontemporal_load(col + e);
      int   r1 = __builtin_nontemporal_load(row + e + T);
      int   c1 = __builtin_nontemporal_load(col + e + T);
      float v0 = __builtin_nontemporal_load(val + e);
      float v1 = __builtin_nontemporal_load(val + e + T);
      edge_body(Ah, r0, c0, v0, eS, tr, m);
      edge_body(Ah, r1, c1, v1, eS, tr, m);
    }
    for (; e < E; e += T)
      edge_body(Ah, row[e], col[e], val[e], eS, tr, m);

    float vals[18];
    vals[0] = eS; vals[1] = tr;
#pragma unroll
    for (int i = 0; i < 16; i++) vals[2 + i] = m[i];
#pragma unroll
    for (int i = 0; i < 18; i++) {
      float v = vals[i];
      for (int off = 32; off; off >>= 1) v += __shfl_xor(v, off, 64);
      vals[i] = v;
    }
    int lane = t & 63, wid = t >> 6;
    if (lane == 0) {
#pragma unroll
      for (int i = 0; i < 18; i++) red[wid][i] = vals[i];
    }
    __syncthreads();
    if (t < 18)
      ep[(size_t)eb * 18 + t] =
          red[0][t] + red[1][t] + red[2][t] + red[3][t];
  } else {
    // ---------------- nodeB role: nb in [0, GB_BLOCKS)
    int nb = b / 5;
    int lane = t & 63;             // channel pair: c = 2*lane, 2*lane+1
    int wid = t >> 6;              // 0..3 — wave owns its own node stream

    float2 acc[16];
#pragma unroll
    for (int k = 0; k < 16; k++) acc[k] = make_float2(0.f, 0.f);

    const float2v* F2 = (const float2v*)F;
    const float4* A4 = (const float4*)A;
    const int stride = GB_BLOCKS * 4;
    for (int n = nb * 4 + wid; n < N; n += stride) {
      float2v f = __builtin_nontemporal_load(&F2[(size_t)n * 64 + lane]);
      float4 a0 = A4[(size_t)n * 4 + 0];
      float4 a1 = A4[(size_t)n * 4 + 1];
      float4 a2 = A4[(size_t)n * 4 + 2];
      float4 a3 = A4[(size_t)n * 4 + 3];
      float av[16] = {a0.x, a0.y, a0.z, a0.w, a1.x, a1.y, a1.z, a1.w,
                      a2.x, a2.y, a2.z, a2.w, a3.x, a3.y, a3.z, a3.w};
#pragma unroll
      for (int k = 0; k < 16; k++) {
        acc[k].x = fmaf(av[k], f.x, acc[k].x);
        acc[k].y = fmaf(av[k], f.y, acc[k].y);
      }
    }
    // each wave writes its own partial row — no reduction needed
    float* myrow = bp + (size_t)(nb * 4 + wid) * 2048;
#pragma unroll
    for (int k = 0; k < 16; k++)
      *(float2*)&myrow[k * 128 + lane * 2] = acc[k];
  }
}

// ---------------------------------------------------------------- k_reduce
// 258 blocks. GB now = 2048 partial rows. (structure unchanged)
__global__ __launch_bounds__(256) void k_reduce(
    const float* __restrict__ csp, const float* __restrict__ ep,
    const float* __restrict__ bp, float* __restrict__ ws,
    int GA, int GE, int GB) {
  __shared__ float L[256];
  int t = threadIdx.x;
  int b = blockIdx.x;
  if (b < 256) {
    int cell = b * 8 + (t & 7);
    int seg = t >> 3;                      // 0..31
    float s0 = 0.f, s1 = 0.f, s2 = 0.f, s3 = 0.f;
    int g = seg;
    for (; g + 96 < GB; g += 128) {
      s0 += bp[(size_t)g * 2048 + cell];
      s1 += bp[(size_t)(g + 32) * 2048 + cell];
      s2 += bp[(size_t)(g + 64) * 2048 + cell];
      s3 += bp[(size_t)(g + 96) * 2048 + cell];
    }
    for (; g < GB; g += 32) s0 += bp[(size_t)g * 2048 + cell];
    L[t] = (s0 + s1) + (s2 + s3);
    __syncthreads();
    if (t < 8) {
      float tot = 0.f;
#pragma unroll
      for (int s = 0; s < 32; s++) tot += L[s * 8 + t];
      ws[WS_B + b * 8 + t] = tot;
    }
  } else if (b == 256) {
    int n = GE * 18;
    float s0 = 0.f, s1 = 0.f, s2 = 0.f, s3 = 0.f;
    if (t < 252) {
      int f = t;
      for (; f + 756 < n; f += 1008) {
        s0 += ep[f]; s1 += ep[f + 252]; s2 += ep[f + 504]; s3 += ep[f + 756];
      }
      for (; f < n; f += 252) s0 += ep[f];
    }
    L[t] = (s0 + s1) + (s2 + s3);
    __syncthreads();
    if (t < 18) {
      float tot = 0.f;
#pragma unroll
      for (int j = 0; j < 14; j++) tot += L[j * 18 + t];
      ws[t] = tot;                        // E_sum, tr, m[16]
    }
  } else {
    int n = GA * 16;
    float s0 = 0.f, s1 = 0.f, s2 = 0.f, s3 = 0.f;
    int f = t;
    for (; f + 768 < n; f += 1024) {
      s0 += csp[f]; s1 += csp[f + 256]; s2 += csp[f + 512]; s3 += csp[f + 768];
    }
    for (; f < n; f += 256) s0 += csp[f];
    L[t] = (s0 + s1) + (s2 + s3);
    __syncthreads();
    if (t < 16) {
      float tot = 0.f;
#pragma unroll
      for (int j = 0; j < 16; j++) tot += L[j * 16 + t];
      ws[WS_CS + t] = tot;
    }
  }
}

// ---------------------------------------------------------------- k_unpool
// out[n,c] = sum_k A[n,k] * P2[k,c]   (runs LAST — overwrites scratch)
// v3: finalize folded in — every block recomputes P2 (2048 selu) in LDS
// from ws B + cs (cheap, removes a kernel launch); block 0 emits the loss.
// P2 hoisted into 16 float4 registers; nontemporal float4 stores (51 MB
// write-once stream should not pollute L2).
__global__ __launch_bounds__(256) void k_unpool(
    const float* __restrict__ A, float* __restrict__ ws,
    float* __restrict__ out, float* __restrict__ loss_out, int N) {
  __shared__ float Ps[2048];
  __shared__ float invcs[16];
  int t = threadIdx.x;
  if (t < 16) invcs[t] = 1.0f / ws[WS_CS + t];
  __syncthreads();
  const float scale = 1.0507009873554805f;
  const float alpha = 1.6732632423543772f;
#pragma unroll
  for (int i = 0; i < 8; i++) {
    int idx = t + 256 * i;
    int k = idx >> 7;
    float x = ws[WS_B + idx] * invcs[k];
    float s = (x > 0.f) ? scale * x : scale * alpha * expm1f(x);
    Ps[idx] = s * invcs[k];
  }
  __syncthreads();

  if (blockIdx.x == 0 && t == 0) {
    float Es = ws[WS_ESUM], tr = ws[WS_TR];
    float m2 = 0.f;
#pragma unroll
    for (int i = 0; i < 16; i++) m2 += ws[WS_M + i] * ws[WS_M + i];
    float spectral = -(tr - m2 / (2.0f * Es)) / (2.0f * Es);
    float coll = 0.f;
    float tgt = (float)N / 16.0f;
#pragma unroll
    for (int i = 0; i < 16; i++) coll += fabsf(ws[WS_CS + i] - tgt);
    coll = coll / (float)N * (4.0f / 3.0f / 2.0f);  // sk/(sk-1)/2, sk=4
    loss_out[0] = spectral + coll;
  }

  int c4 = (t & 31) << 2;          // channel base (0,4,...,124)
  int sub = t >> 5;                // 0..7 (node within group)
  float4 pk[16];
#pragma unroll
  for (int k = 0; k < 16; k++) pk[k] = *(const float4*)&Ps[k * 128 + c4];

  int stride = gridDim.x * 8;
  for (int n = blockIdx.x * 8 + sub; n < N; n += stride) {
    const float4* a4 = (const float4*)(A + (size_t)n * 16);
    float4 a0 = a4[0], a1 = a4[1], a2 = a4[2], a3 = a4[3];
    float av[16] = {a0.x, a0.y, a0.z, a0.w, a1.x, a1.y, a1.z, a1.w,
                    a2.x, a2.y, a2.z, a2.w, a3.x, a3.y, a3.z, a3.w};
    float4v s = {0.f, 0.f, 0.f, 0.f};
#pragma unroll
    for (int k = 0; k < 16; k++) {
      s.x = fmaf(av[k], pk[k].x, s.x);
      s.y = fmaf(av[k], pk[k].y, s.y);
      s.z = fmaf(av[k], pk[k].z, s.z);
      s.w = fmaf(av[k], pk[k].w, s.w);
    }
    __builtin_nontemporal_store(s, (float4v*)(out + (size_t)n * 128 + c4));
  }
}

// ----------------------------------------------------------------
extern "C" void kernel_launch(void* const* d_in, const int* in_sizes, int n_in,
                              void* d_out, int out_size, void* d_ws, size_t ws_size,
                              hipStream_t stream) {
  const float* F    = (const float*)d_in[0];  // [N,128]
  const int*   erow = (const int*)d_in[1];    // [E]
  const int*   ecol = (const int*)d_in[2];    // [E]
  const float* eval_= (const float*)d_in[3];  // [E]
  const float* W    = (const float*)d_in[4];  // [16,128]
  const float* bias = (const float*)d_in[5];  // [16]

  int N = in_sizes[0] / 128;
  int E = in_sizes[1];

  float* out0 = (float*)d_out;                 // features_pooled [N,128]
  float* A    = out0 + (size_t)N * 128;        // assignments [N,16]
  float* loss = A + (size_t)N * 16;            // scalar
  float* ws   = (float*)d_ws;

  int GA = (N + 127) / 128;                    // k_assign grid (782)
  int GE = GE_BLOCKS;                          // 2048 edge-role blocks
  int GBp = GB_BLOCKS * 4;                     // 2048 bp partial rows

  // scratch inside the (not-yet-written) features_pooled output region
  __half* Ah  = (__half*)(out0 + OFF_AH);      // [N][16] fp16, 3.2 MB
  float*  csp = out0 + OFF_CSP;                // [GA][16]
  float*  ep  = out0 + OFF_EP;                 // [2048][18]
  float*  bp  = out0 + OFF_BP;                 // [2048][2048], 16.8 MB

  k_assign<<<GA, 256, 0, stream>>>(F, W, bias, A, Ah, csp, N);
  k_edge_nodeB<<<GE_BLOCKS + GB_BLOCKS, 256, 0, stream>>>(
      erow, ecol, eval_, Ah, F, A, ep, bp, E, N);
  k_reduce<<<258, 256, 0, stream>>>(csp, ep, bp, ws, GA, GE, GBp);
  k_unpool<<<1280, 256, 0, stream>>>(A, ws, out0, loss, N);
}